// Round 12
// baseline (227.117 us; speedup 1.0000x reference)
//
#include <hip/hip_runtime.h>
#include <stdint.h>

#define HD 128
#define EPS 1e-5f
#define NPB 256           // nodes per bucket (dst-local fits 8 bits)
#define SENT 0xFFFFFFFFu

typedef __attribute__((ext_vector_type(8))) short bf16x8;
typedef __attribute__((ext_vector_type(4))) float f32x4;

// bf16 pack/unpack (RNE), explicit bit layout: low ushort = even col.
__device__ inline unsigned bf_round(float f) {
  unsigned u = __float_as_uint(f);
  return (u + 0x7fffu + ((u >> 16) & 1u)) >> 16;
}
__device__ inline unsigned bf_pack2(float x, float y) {
  return bf_round(x) | (bf_round(y) << 16);
}
__device__ inline float2 bf_unpack2(unsigned u) {
  float2 r;
  r.x = __uint_as_float(u << 16);
  r.y = __uint_as_float(u & 0xffff0000u);
  return r;
}
__device__ inline float bf_up(unsigned short us) {
  return __uint_as_float(((unsigned)us) << 16);
}

// ---------------- prep: W transposes, counter zeroing, per-graph invcnt + out init ----------------
__global__ void k_prep(const float* __restrict__ W1, const float* __restrict__ W2,
                       unsigned short* __restrict__ Wt1, unsigned short* __restrict__ Wt2,
                       int* __restrict__ bline, float* __restrict__ sums1,
                       float* __restrict__ sums2, int nbline,
                       const int* __restrict__ batch, float* __restrict__ invcnt,
                       const float* __restrict__ bout, float* __restrict__ out,
                       int G, int N, int zblocks) {
  int b = blockIdx.x, t = threadIdx.x;
  if (b < 64) {
    int e = b * 256 + t;
    int k = e >> 7, c = e & 127;
    Wt1[c * 128 + k] = (unsigned short)bf_round(W1[e]);
  } else if (b < 128) {
    int e = (b - 64) * 256 + t;
    int k = e >> 7, c = e & 127;
    Wt2[c * 128 + k] = (unsigned short)bf_round(W2[e]);
  } else if (b < 128 + zblocks) {
    int i = (b - 128) * 256 + t;
    if (i < nbline) bline[i] = 0;
    if (i < 256) { sums1[i] = 0.f; sums2[i] = 0.f; }
  } else {
    int g = (b - 128 - zblocks) * 256 + t;
    if (g < G) {
      int lo = 0, hi = N;  // first index with batch[i] >= g
      while (lo < hi) { int mid = (lo + hi) >> 1; if (batch[mid] < g) lo = mid + 1; else hi = mid; }
      int lb = lo;
      hi = N;              // first index with batch[i] > g
      while (lo < hi) { int mid = (lo + hi) >> 1; if (batch[mid] <= g) lo = mid + 1; else hi = mid; }
      float cnt = (float)(lo - lb);
      invcnt[g] = 1.0f / fmaxf(cnt, 1.0f);
      out[g] = bout[0];   // pooling adds on top (finalnode atomics)
    }
  }
}

// ---------------- Phase A: bucket-bin edges with per-wg line reservation (R10 version) ----------------
__global__ __launch_bounds__(256) void k_phaseA(const int* __restrict__ src, const int* __restrict__ dst,
                                                int* __restrict__ bline, unsigned* __restrict__ arena,
                                                int E, int NBKT, int capLines, int chunk) {
  __shared__ int hist[NPB], gbase[NPB], ccap[NPB], lpos[NPB];
  const int t = threadIdx.x;
  for (int i = t; i < NPB; i += 256) { hist[i] = 0; lpos[i] = 0; }
  __syncthreads();
  const int e0 = blockIdx.x * chunk;
  const int e1 = (e0 + chunk < E) ? e0 + chunk : E;
  for (int i = e0 + t; i < e1; i += 256) atomicAdd(&hist[dst[i] >> 8], 1);
  __syncthreads();
  for (int b = t; b < NBKT; b += 256) {
    int n = hist[b];
    int nl = (n + 15) >> 4;
    int base = nl ? atomicAdd(&bline[b * 16], nl) : 0;
    if (base + nl > capLines) nl = (base < capLines) ? capLines - base : 0;
    gbase[b] = b * capLines * 16 + base * 16;
    ccap[b] = nl * 16;
  }
  __syncthreads();
  for (int i = e0 + t; i < e1; i += 256) {
    int d = dst[i];
    int b = d >> 8;
    int lp = atomicAdd(&lpos[b], 1);
    if (lp < ccap[b]) arena[gbase[b] + lp] = ((unsigned)src[i] << 8) | (unsigned)(d & 255);
  }
  __syncthreads();
  for (int b = t; b < NBKT; b += 256) {
    int n = lpos[b] < ccap[b] ? lpos[b] : ccap[b];
    for (int j = n; j < ccap[b]; ++j) arena[gbase[b] + j] = SENT;
  }
}

// ---------------- Phase B: per-bucket CSR finalize ----------------
__global__ __launch_bounds__(256) void k_phaseB(const unsigned* __restrict__ arena,
                                                const int* __restrict__ bline,
                                                unsigned short* __restrict__ colidx,
                                                unsigned* __restrict__ nodeinfo,
                                                float* __restrict__ dinv,
                                                int N, int capLines) {
  __shared__ int deg[NPB], pos[NPB], scan[NPB];
  const int b = blockIdx.x;
  const int t = threadIdx.x;
  deg[t] = 0;
  __syncthreads();
  int used = bline[b * 16];
  if (used > capLines) used = capLines;
  const int slots = used * 16;
  const unsigned* seg = arena + (size_t)b * capLines * 16;
  for (int s = t; s < slots; s += 256) {
    unsigned u = seg[s];
    if (u != SENT) atomicAdd(&deg[u & 255], 1);
  }
  __syncthreads();
  int v = deg[t];
  scan[t] = v;
  __syncthreads();
  for (int off = 1; off < 256; off <<= 1) {
    int tv = (t >= off) ? scan[t - off] : 0;
    __syncthreads();
    scan[t] += tv;
    __syncthreads();
  }
  int prefix = scan[t] - v;  // exclusive
  pos[t] = prefix;
  int n = b * NPB + t;
  if (n < N) {
    unsigned off = (unsigned)(b * capLines * 16 + prefix);
    unsigned d8 = (unsigned)(v < 255 ? v : 255);
    nodeinfo[n] = (off << 8) | d8;
    dinv[n] = rsqrtf((float)v + 1.0f);
  }
  __syncthreads();
  unsigned short* cseg = colidx + (size_t)b * capLines * 16;
  for (int s = t; s < slots; s += 256) {
    unsigned u = seg[s];
    if (u != SENT) {
      int p = atomicAdd(&pos[u & 255], 1);
      cseg[p] = (unsigned short)(u >> 8);
    }
  }
}

// ---------------- MFMA GEMM (R10 version: BM=64, 256 thr): Yp[r][c] = bf16( dinv[r]*(bnrelu?(A[r])@W)[c] ) ----------------
// A-fragments direct global->reg; only W staged in LDS. Plain ushort epilogue stores.
#define SAB_LD 136  // bf16 elems; 272B rows: 16B-aligned, <=2-way LDS bank aliasing (free)
__global__ __launch_bounds__(256) void k_gemm(const float* __restrict__ Af32,
                                              const unsigned short* __restrict__ Abf,
                                              const unsigned short* __restrict__ Wt,
                                              unsigned short* __restrict__ Yp, int N,
                                              const float* __restrict__ dinv,
                                              const float* __restrict__ sums,
                                              const float* __restrict__ gamma,
                                              const float* __restrict__ beta, float invN) {
  __shared__ unsigned short sWt[128 * SAB_LD];  // 34.8 KB, [col][k]
  __shared__ float sSc[128], sSh[128];
  const int tid = threadIdx.x;
  const int row0 = blockIdx.x * 64;
  // stage pre-transposed W: coalesced uint4 copy (8 bf16 along k)
  for (int i = tid * 8; i < 128 * 128; i += 256 * 8) {
    int c = i >> 7, k = i & 127;
    *(uint4*)&sWt[c * SAB_LD + k] = *(const uint4*)&Wt[i];
  }
  // BN params (layer 2): deterministic identical compute per block
  if (sums && tid < 128) {
    float mean = sums[tid] * invN;
    float var = sums[128 + tid] * invN - mean * mean;
    float sc = gamma[tid] * rsqrtf(var + EPS);
    sSc[tid] = sc;
    sSh[tid] = beta[tid] - mean * sc;
  }
  __syncthreads();
  const int w = tid >> 6;        // wave id: rows 16w..16w+15
  const int l = tid & 63;
  const int lr = l & 15;         // A row-in-tile / B,D col-in-tile
  const int lk = (l >> 4) * 8;   // k-offset base
  const int arow = row0 + w * 16 + lr;
  const bool rv = arow < N;
  f32x4 acc[8];
#pragma unroll
  for (int t = 0; t < 8; ++t) acc[t] = (f32x4){0.f, 0.f, 0.f, 0.f};
#pragma unroll
  for (int kk = 0; kk < 128; kk += 32) {
    bf16x8 af;
    if (!Abf) {  // layer 1: f32 source, round to bf16 in-register
      float4 f0 = make_float4(0.f, 0.f, 0.f, 0.f), f1 = f0;
      if (rv) {
        f0 = *(const float4*)&Af32[(size_t)arow * HD + kk + lk];
        f1 = *(const float4*)&Af32[(size_t)arow * HD + kk + lk + 4];
      }
      af[0] = (short)bf_round(f0.x); af[1] = (short)bf_round(f0.y);
      af[2] = (short)bf_round(f0.z); af[3] = (short)bf_round(f0.w);
      af[4] = (short)bf_round(f1.x); af[5] = (short)bf_round(f1.y);
      af[6] = (short)bf_round(f1.z); af[7] = (short)bf_round(f1.w);
    } else {     // layer 2: bf16 source + fused BN+ReLU in-register
      bf16x8 raw = (bf16x8){0, 0, 0, 0, 0, 0, 0, 0};
      if (rv) raw = *(const bf16x8*)&Abf[(size_t)arow * HD + kk + lk];
      float4 c0 = *(const float4*)&sSc[kk + lk];
      float4 c1 = *(const float4*)&sSc[kk + lk + 4];
      float4 h0 = *(const float4*)&sSh[kk + lk];
      float4 h1 = *(const float4*)&sSh[kk + lk + 4];
      float vv;
#define BNAPP(i, sc, sh) \
      vv = bf_up((unsigned short)raw[i]); \
      vv = fmaxf(0.f, vv * (sc) + (sh)); \
      af[i] = (short)bf_round(vv);
      BNAPP(0, c0.x, h0.x) BNAPP(1, c0.y, h0.y) BNAPP(2, c0.z, h0.z) BNAPP(3, c0.w, h0.w)
      BNAPP(4, c1.x, h1.x) BNAPP(5, c1.y, h1.y) BNAPP(6, c1.z, h1.z) BNAPP(7, c1.w, h1.w)
#undef BNAPP
    }
#pragma unroll
    for (int t = 0; t < 8; ++t) {
      bf16x8 bfr = *(const bf16x8*)&sWt[(t * 16 + lr) * SAB_LD + kk + lk];
      acc[t] = __builtin_amdgcn_mfma_f32_16x16x32_bf16(af, bfr, acc[t], 0, 0, 0);
    }
  }
  // epilogue: scale by dinv, store ushort per lane (D row = 4*(l>>4)+j, col = t*16+lr)
  const int rbase = row0 + w * 16 + (l >> 4) * 4;
#pragma unroll
  for (int j = 0; j < 4; ++j) {
    int r = rbase + j;
    if (r >= N) continue;
    float d = dinv[r];
#pragma unroll
    for (int t = 0; t < 8; ++t) {
      Yp[(size_t)r * HD + t * 16 + lr] = (unsigned short)bf_round(acc[t][j] * d);
    }
  }
}

// ---------------- aggregate: Out[n] = bf16( dinv[n]*(Yp[n] + sum_{s in N(n)} Yp[s]) ) ----------------
__global__ __launch_bounds__(256) void k_aggregate(const unsigned* __restrict__ Yp,
                                                   const unsigned* __restrict__ nodeinfo,
                                                   const unsigned short* __restrict__ colidx,
                                                   const float* __restrict__ dinv,
                                                   unsigned* __restrict__ Out, int N) {
  int n = (blockIdx.x * blockDim.x + threadIdx.x) >> 6;  // one wave per node
  int lane = threadIdx.x & 63;
  if (n >= N) return;
  const int sl = lane & 31;
  const int hid = lane >> 5;   // half id: reads rows j+hid
  const unsigned info = nodeinfo[n];
  const int beg = (int)(info >> 8);
  const int deg = (int)(info & 255);
  float a0 = 0.f, a1 = 0.f, a2 = 0.f, a3 = 0.f;  // cols 4sl..4sl+3
  if (hid == 0) {  // self row once
    uint2 u = *(const uint2*)&Yp[(size_t)n * 64 + sl * 2];
    float2 p0 = bf_unpack2(u.x), p1 = bf_unpack2(u.y);
    a0 = p0.x; a1 = p0.y; a2 = p1.x; a3 = p1.y;
  }
  for (int base = 0; base < deg; base += 64) {
    int cnt = deg - base; if (cnt > 64) cnt = 64;
    int nbr = (lane < cnt) ? (int)colidx[beg + base + lane] : 0;
    int j = 0;
    for (; j + 16 <= cnt; j += 16) {  // 8 uint2 loads in flight = 16 rows
      int s0 = __shfl(nbr, j + 0 + hid, 64);
      int s1 = __shfl(nbr, j + 2 + hid, 64);
      int s2 = __shfl(nbr, j + 4 + hid, 64);
      int s3 = __shfl(nbr, j + 6 + hid, 64);
      int s4 = __shfl(nbr, j + 8 + hid, 64);
      int s5 = __shfl(nbr, j + 10 + hid, 64);
      int s6 = __shfl(nbr, j + 12 + hid, 64);
      int s7 = __shfl(nbr, j + 14 + hid, 64);
      uint2 q0 = *(const uint2*)&Yp[(size_t)s0 * 64 + sl * 2];
      uint2 q1 = *(const uint2*)&Yp[(size_t)s1 * 64 + sl * 2];
      uint2 q2 = *(const uint2*)&Yp[(size_t)s2 * 64 + sl * 2];
      uint2 q3 = *(const uint2*)&Yp[(size_t)s3 * 64 + sl * 2];
      uint2 q4 = *(const uint2*)&Yp[(size_t)s4 * 64 + sl * 2];
      uint2 q5 = *(const uint2*)&Yp[(size_t)s5 * 64 + sl * 2];
      uint2 q6 = *(const uint2*)&Yp[(size_t)s6 * 64 + sl * 2];
      uint2 q7 = *(const uint2*)&Yp[(size_t)s7 * 64 + sl * 2];
      float2 x0 = bf_unpack2(q0.x), y0 = bf_unpack2(q0.y);
      float2 x1 = bf_unpack2(q1.x), y1 = bf_unpack2(q1.y);
      float2 x2 = bf_unpack2(q2.x), y2 = bf_unpack2(q2.y);
      float2 x3 = bf_unpack2(q3.x), y3 = bf_unpack2(q3.y);
      float2 x4 = bf_unpack2(q4.x), y4 = bf_unpack2(q4.y);
      float2 x5 = bf_unpack2(q5.x), y5 = bf_unpack2(q5.y);
      float2 x6 = bf_unpack2(q6.x), y6 = bf_unpack2(q6.y);
      float2 x7 = bf_unpack2(q7.x), y7 = bf_unpack2(q7.y);
      a0 += ((x0.x + x1.x) + (x2.x + x3.x)) + ((x4.x + x5.x) + (x6.x + x7.x));
      a1 += ((x0.y + x1.y) + (x2.y + x3.y)) + ((x4.y + x5.y) + (x6.y + x7.y));
      a2 += ((y0.x + y1.x) + (y2.x + y3.x)) + ((y4.x + y5.x) + (y6.x + y7.x));
      a3 += ((y0.y + y1.y) + (y2.y + y3.y)) + ((y4.y + y5.y) + (y6.y + y7.y));
    }
    for (; j + 2 <= cnt; j += 2) {  // pair tail
      int s = __shfl(nbr, j + hid, 64);
      uint2 q = *(const uint2*)&Yp[(size_t)s * 64 + sl * 2];
      float2 x = bf_unpack2(q.x), y = bf_unpack2(q.y);
      a0 += x.x; a1 += x.y; a2 += y.x; a3 += y.y;
    }
    if (j < cnt) {  // odd last row: half 0 only
      int s = __shfl(nbr, j, 64);
      if (hid == 0) {
        uint2 q = *(const uint2*)&Yp[(size_t)s * 64 + sl * 2];
        float2 x = bf_unpack2(q.x), y = bf_unpack2(q.y);
        a0 += x.x; a1 += x.y; a2 += y.x; a3 += y.y;
      }
    }
  }
  // combine halves (cols identical across halves)
  a0 += __shfl_xor(a0, 32, 64);
  a1 += __shfl_xor(a1, 32, 64);
  a2 += __shfl_xor(a2, 32, 64);
  a3 += __shfl_xor(a3, 32, 64);
  if (hid == 0) {
    float dd = dinv[n];
    unsigned lo = bf_pack2(a0 * dd, a1 * dd);
    unsigned hi = bf_pack2(a2 * dd, a3 * dd);
    *(uint2*)&Out[(size_t)n * 64 + sl * 2] = make_uint2(lo, hi);
  }
}

// ---------------- per-column sum / sumsq over bf16-packed X ----------------
__global__ __launch_bounds__(256) void k_colstats(const unsigned* __restrict__ X, int N,
                                                  float* __restrict__ sums) {
  const int c2 = threadIdx.x & 63;   // packed col pair
  const int half = threadIdx.x >> 6; // 4-way row split
  float sx = 0.f, sy = 0.f, qx = 0.f, qy = 0.f;
  for (int r = blockIdx.x * 4 + half; r < N; r += gridDim.x * 4) {
    float2 v = bf_unpack2(X[(size_t)r * 64 + c2]);
    sx += v.x; sy += v.y; qx += v.x * v.x; qy += v.y * v.y;
  }
  __shared__ float l0[256], l1[256], l2[256], l3[256];
  l0[threadIdx.x] = sx; l1[threadIdx.x] = sy; l2[threadIdx.x] = qx; l3[threadIdx.x] = qy;
  __syncthreads();
  if (threadIdx.x < 64) {
    int t = threadIdx.x;
    sx = l0[t] + l0[t + 64] + l0[t + 128] + l0[t + 192];
    sy = l1[t] + l1[t + 64] + l1[t + 128] + l1[t + 192];
    qx = l2[t] + l2[t + 64] + l2[t + 128] + l2[t + 192];
    qy = l3[t] + l3[t + 64] + l3[t + 128] + l3[t + 192];
    int c = t * 2;
    atomicAdd(&sums[c], sx);
    atomicAdd(&sums[c + 1], sy);
    atomicAdd(&sums[128 + c], qx);
    atomicAdd(&sums[129 + c], qy);
  }
}

// ---------------- fused BN2+ReLU+dot(Wout)+pool: atomicAdd(p*invcnt) into out (pre-init to bout) ----------------
__global__ __launch_bounds__(256) void k_finalnode(const unsigned* __restrict__ Agg,
                                                   const float* __restrict__ sums,
                                                   const float* __restrict__ gamma,
                                                   const float* __restrict__ beta,
                                                   const float* __restrict__ wout,
                                                   const int* __restrict__ batch,
                                                   const float* __restrict__ invcnt,
                                                   float* __restrict__ out,
                                                   int N, float invN) {
  int n = (blockIdx.x * blockDim.x + threadIdx.x) >> 6;
  int lane = threadIdx.x & 63;
  if (n >= N) return;
  int c = lane * 2;
  float mean0 = sums[c] * invN;
  float var0 = sums[128 + c] * invN - mean0 * mean0;
  float sc0 = gamma[c] * rsqrtf(var0 + EPS);
  float sh0 = beta[c] - mean0 * sc0;
  float mean1 = sums[c + 1] * invN;
  float var1 = sums[129 + c] * invN - mean1 * mean1;
  float sc1 = gamma[c + 1] * rsqrtf(var1 + EPS);
  float sh1 = beta[c + 1] - mean1 * sc1;
  float2 v = bf_unpack2(Agg[(size_t)n * 64 + lane]);
  float h0 = fmaxf(0.f, v.x * sc0 + sh0);
  float h1 = fmaxf(0.f, v.y * sc1 + sh1);
  float p = h0 * wout[c] + h1 * wout[c + 1];
  for (int off = 32; off > 0; off >>= 1) p += __shfl_down(p, off);
  if (lane == 0) {
    int g = batch[n];
    atomicAdd(&out[g], p * invcnt[g]);
  }
}

extern "C" void kernel_launch(void* const* d_in, const int* in_sizes, int n_in,
                              void* d_out, int out_size, void* d_ws, size_t ws_size,
                              hipStream_t stream) {
  (void)n_in; (void)ws_size;
  const float* x      = (const float*)d_in[0];
  const int*   ei     = (const int*)d_in[1];
  const int*   batch  = (const int*)d_in[2];
  const float* W1     = (const float*)d_in[3];
  const float* gamma1 = (const float*)d_in[5];
  const float* beta1  = (const float*)d_in[6];
  const float* W2     = (const float*)d_in[7];
  const float* gamma2 = (const float*)d_in[9];
  const float* beta2  = (const float*)d_in[10];
  const float* wout   = (const float*)d_in[11];
  const float* bout   = (const float*)d_in[12];
  float* out = (float*)d_out;

  const int N = in_sizes[0] / HD;
  const int E = in_sizes[1] / 2;
  const int G = out_size;
  const int* src = ei;
  const int* dst = ei + E;
  const int NBKT = (N + NPB - 1) / NPB;
  const int NWGA = 256;
  const int chunk = (E + NWGA - 1) / NWGA;
  const int capLines = E / (NBKT * 16) + NWGA + 64;
  const int capSlots = capLines * 16;
  const float invN = 1.0f / (float)N;

  char* p = (char*)d_ws;
  auto carve = [&](size_t bytes) { char* r = p; p += (bytes + 255) & ~(size_t)255; return r; };
  unsigned* bufY = (unsigned*)carve((size_t)N * 64 * 4);     // bf16 Y' [N,128] (ushort rows)
  unsigned* bufAgg = (unsigned*)carve((size_t)N * 64 * 4);   // bf16 Agg [N,128]
  unsigned* arena = (unsigned*)carve((size_t)NBKT * capSlots * 4);
  unsigned short* colidx = (unsigned short*)carve((size_t)NBKT * capSlots * 2);
  unsigned short* Wt1 = (unsigned short*)carve(128 * 128 * 2);
  unsigned short* Wt2 = (unsigned short*)carve(128 * 128 * 2);
  unsigned* nodeinfo = (unsigned*)carve((size_t)N * 4);
  float* dinv    = (float*)carve((size_t)N * 4);
  float* invcnt  = (float*)carve((size_t)G * 4);
  int*   bline = (int*)carve((size_t)NBKT * 16 * 4);
  float* sums1 = (float*)carve(256 * 4);
  float* sums2 = (float*)carve(256 * 4);

  const int nbline = NBKT * 16;
  const int zblocks = (nbline + 255) / 256;
  const int gb2 = (G + 255) / 256;
  const int pblocks = 128 + zblocks + gb2;
  k_prep<<<pblocks, 256, 0, stream>>>(W1, W2, Wt1, Wt2, bline, sums1, sums2, nbline,
                                      batch, invcnt, bout, out, G, N, zblocks);

  // CSR build (2 kernels)
  k_phaseA<<<NWGA, 256, 0, stream>>>(src, dst, bline, arena, E, NBKT, capLines, chunk);
  k_phaseB<<<NBKT, 256, 0, stream>>>(arena, bline, colidx, nodeinfo, dinv, N, capLines);

  const int gblocks = (N + 63) / 64;
  const int ablocks = (N + 3) / 4;
  // layer 1 (A direct from f32 x)
  k_gemm<<<gblocks, 256, 0, stream>>>(x, nullptr, Wt1, (unsigned short*)bufY, N, dinv,
                                      nullptr, nullptr, nullptr, invN);
  k_aggregate<<<ablocks, 256, 0, stream>>>(bufY, nodeinfo, colidx, dinv, bufAgg, N);
  k_colstats<<<512, 256, 0, stream>>>(bufAgg, N, sums1);
  // layer 2 (A direct from bf16 bufAgg; BN1+ReLU fused in-register)
  k_gemm<<<gblocks, 256, 0, stream>>>(nullptr, (const unsigned short*)bufAgg, Wt2,
                                      (unsigned short*)bufY, N, dinv, sums1, gamma1, beta1, invN);
  k_aggregate<<<ablocks, 256, 0, stream>>>(bufY, nodeinfo, colidx, dinv, bufAgg, N);
  k_colstats<<<512, 256, 0, stream>>>(bufAgg, N, sums2);
  // output head: BN2+ReLU+proj+mean-pool fused, adds into pre-initialized out
  k_finalnode<<<ablocks, 256, 0, stream>>>(bufAgg, sums2, gamma2, beta2, wout, batch,
                                           invcnt, out, N, invN);
}

// Round 13
// 216.758 us; speedup vs baseline: 1.0478x; 1.0478x over previous
//
#include <hip/hip_runtime.h>
#include <stdint.h>

#define HD 128
#define EPS 1e-5f
#define NPB 256           // nodes per bucket (dst-local fits 8 bits)
#define SENT 0xFFFFFFFFu

typedef __attribute__((ext_vector_type(8))) short bf16x8;
typedef __attribute__((ext_vector_type(4))) float f32x4;

// bf16 pack/unpack (RNE), explicit bit layout: low ushort = even col.
__device__ inline unsigned bf_round(float f) {
  unsigned u = __float_as_uint(f);
  return (u + 0x7fffu + ((u >> 16) & 1u)) >> 16;
}
__device__ inline unsigned bf_pack2(float x, float y) {
  return bf_round(x) | (bf_round(y) << 16);
}
__device__ inline float2 bf_unpack2(unsigned u) {
  float2 r;
  r.x = __uint_as_float(u << 16);
  r.y = __uint_as_float(u & 0xffff0000u);
  return r;
}
__device__ inline float bf_up(unsigned short us) {
  return __uint_as_float(((unsigned)us) << 16);
}

// ---------------- prep: W1,W2 -> bf16 transposed [col][k]; zero counters ----------------
__global__ void k_prep(const float* __restrict__ W1, const float* __restrict__ W2,
                       unsigned short* __restrict__ Wt1, unsigned short* __restrict__ Wt2,
                       int* __restrict__ bline, float* __restrict__ sums1,
                       float* __restrict__ sums2, int nbline) {
  int b = blockIdx.x, t = threadIdx.x;
  if (b < 64) {
    int e = b * 256 + t;
    int k = e >> 7, c = e & 127;
    Wt1[c * 128 + k] = (unsigned short)bf_round(W1[e]);
  } else if (b < 128) {
    int e = (b - 64) * 256 + t;
    int k = e >> 7, c = e & 127;
    Wt2[c * 128 + k] = (unsigned short)bf_round(W2[e]);
  } else {
    int i = (b - 128) * 256 + t;
    if (i < nbline) bline[i] = 0;
    if (i < 256) { sums1[i] = 0.f; sums2[i] = 0.f; }
  }
}

// ---------------- Phase A: bucket-bin edges with per-wg line reservation ----------------
__global__ __launch_bounds__(256) void k_phaseA(const int* __restrict__ src, const int* __restrict__ dst,
                                                int* __restrict__ bline, unsigned* __restrict__ arena,
                                                int E, int NBKT, int capLines, int chunk) {
  __shared__ int hist[NPB], gbase[NPB], ccap[NPB], lpos[NPB];
  const int t = threadIdx.x;
  for (int i = t; i < NPB; i += 256) { hist[i] = 0; lpos[i] = 0; }
  __syncthreads();
  const int e0 = blockIdx.x * chunk;
  const int e1 = (e0 + chunk < E) ? e0 + chunk : E;
  for (int i = e0 + t; i < e1; i += 256) atomicAdd(&hist[dst[i] >> 8], 1);
  __syncthreads();
  for (int b = t; b < NBKT; b += 256) {
    int n = hist[b];
    int nl = (n + 15) >> 4;
    int base = nl ? atomicAdd(&bline[b * 16], nl) : 0;
    if (base + nl > capLines) nl = (base < capLines) ? capLines - base : 0;
    gbase[b] = b * capLines * 16 + base * 16;
    ccap[b] = nl * 16;
  }
  __syncthreads();
  for (int i = e0 + t; i < e1; i += 256) {
    int d = dst[i];
    int b = d >> 8;
    int lp = atomicAdd(&lpos[b], 1);
    if (lp < ccap[b]) arena[gbase[b] + lp] = ((unsigned)src[i] << 8) | (unsigned)(d & 255);
  }
  __syncthreads();
  for (int b = t; b < NBKT; b += 256) {
    int n = lpos[b] < ccap[b] ? lpos[b] : ccap[b];
    for (int j = n; j < ccap[b]; ++j) arena[gbase[b] + j] = SENT;
  }
}

// ---------------- Phase B: per-bucket CSR finalize ----------------
__global__ __launch_bounds__(256) void k_phaseB(const unsigned* __restrict__ arena,
                                                const int* __restrict__ bline,
                                                unsigned short* __restrict__ colidx,
                                                unsigned* __restrict__ nodeinfo,
                                                float* __restrict__ dinv,
                                                int N, int capLines) {
  __shared__ int deg[NPB], pos[NPB], scan[NPB];
  const int b = blockIdx.x;
  const int t = threadIdx.x;
  deg[t] = 0;
  __syncthreads();
  int used = bline[b * 16];
  if (used > capLines) used = capLines;
  const int slots = used * 16;
  const unsigned* seg = arena + (size_t)b * capLines * 16;
  for (int s = t; s < slots; s += 256) {
    unsigned u = seg[s];
    if (u != SENT) atomicAdd(&deg[u & 255], 1);
  }
  __syncthreads();
  int v = deg[t];
  scan[t] = v;
  __syncthreads();
  for (int off = 1; off < 256; off <<= 1) {
    int tv = (t >= off) ? scan[t - off] : 0;
    __syncthreads();
    scan[t] += tv;
    __syncthreads();
  }
  int prefix = scan[t] - v;  // exclusive
  pos[t] = prefix;
  int n = b * NPB + t;
  if (n < N) {
    unsigned off = (unsigned)(b * capLines * 16 + prefix);
    unsigned d8 = (unsigned)(v < 255 ? v : 255);
    nodeinfo[n] = (off << 8) | d8;
    dinv[n] = rsqrtf((float)v + 1.0f);
  }
  __syncthreads();
  unsigned short* cseg = colidx + (size_t)b * capLines * 16;
  for (int s = t; s < slots; s += 256) {
    unsigned u = seg[s];
    if (u != SENT) {
      int p = atomicAdd(&pos[u & 255], 1);
      cseg[p] = (unsigned short)(u >> 8);
    }
  }
}

// ---------------- MFMA GEMM: Yp[r][c] = bf16( dinv[r] * (bnrelu?(A[r]) @ W)[c] ) ----------------
// A-fragments loaded DIRECTLY global->reg (each A element consumed by exactly one lane).
// Only W staged in LDS (reused by all waves). Epilogue: plain ushort stores, no shfl.
#define SAB_LD 136  // bf16 elems; 272B rows: 16B-aligned, <=2-way LDS bank aliasing (free)
__global__ __launch_bounds__(256) void k_gemm(const float* __restrict__ Af32,
                                              const unsigned short* __restrict__ Abf,
                                              const unsigned short* __restrict__ Wt,
                                              unsigned short* __restrict__ Yp, int N,
                                              const float* __restrict__ dinv,
                                              const float* __restrict__ sums,
                                              const float* __restrict__ gamma,
                                              const float* __restrict__ beta, float invN) {
  __shared__ unsigned short sWt[128 * SAB_LD];  // 34.8 KB, [col][k]
  __shared__ float sSc[128], sSh[128];
  const int tid = threadIdx.x;
  const int row0 = blockIdx.x * 64;
  // stage pre-transposed W: coalesced uint4 copy (8 bf16 along k)
  for (int i = tid * 8; i < 128 * 128; i += 256 * 8) {
    int c = i >> 7, k = i & 127;
    *(uint4*)&sWt[c * SAB_LD + k] = *(const uint4*)&Wt[i];
  }
  // BN params (layer 2): deterministic identical compute per block
  if (sums && tid < 128) {
    float mean = sums[tid] * invN;
    float var = sums[128 + tid] * invN - mean * mean;
    float sc = gamma[tid] * rsqrtf(var + EPS);
    sSc[tid] = sc;
    sSh[tid] = beta[tid] - mean * sc;
  }
  __syncthreads();
  const int w = tid >> 6;        // wave id: rows 16w..16w+15
  const int l = tid & 63;
  const int lr = l & 15;         // A row-in-tile / B,D col-in-tile
  const int lk = (l >> 4) * 8;   // k-offset base
  const int arow = row0 + w * 16 + lr;
  const bool rv = arow < N;
  f32x4 acc[8];
#pragma unroll
  for (int t = 0; t < 8; ++t) acc[t] = (f32x4){0.f, 0.f, 0.f, 0.f};
#pragma unroll
  for (int kk = 0; kk < 128; kk += 32) {
    bf16x8 af;
    if (!Abf) {  // layer 1: f32 source, round to bf16 in-register
      float4 f0 = make_float4(0.f, 0.f, 0.f, 0.f), f1 = f0;
      if (rv) {
        f0 = *(const float4*)&Af32[(size_t)arow * HD + kk + lk];
        f1 = *(const float4*)&Af32[(size_t)arow * HD + kk + lk + 4];
      }
      af[0] = (short)bf_round(f0.x); af[1] = (short)bf_round(f0.y);
      af[2] = (short)bf_round(f0.z); af[3] = (short)bf_round(f0.w);
      af[4] = (short)bf_round(f1.x); af[5] = (short)bf_round(f1.y);
      af[6] = (short)bf_round(f1.z); af[7] = (short)bf_round(f1.w);
    } else {     // layer 2: bf16 source + fused BN+ReLU in-register
      bf16x8 raw = (bf16x8){0, 0, 0, 0, 0, 0, 0, 0};
      if (rv) raw = *(const bf16x8*)&Abf[(size_t)arow * HD + kk + lk];
      float4 c0 = *(const float4*)&sSc[kk + lk];
      float4 c1 = *(const float4*)&sSc[kk + lk + 4];
      float4 h0 = *(const float4*)&sSh[kk + lk];
      float4 h1 = *(const float4*)&sSh[kk + lk + 4];
      float vv;
#define BNAPP(i, sc, sh) \
      vv = bf_up((unsigned short)raw[i]); \
      vv = fmaxf(0.f, vv * (sc) + (sh)); \
      af[i] = (short)bf_round(vv);
      BNAPP(0, c0.x, h0.x) BNAPP(1, c0.y, h0.y) BNAPP(2, c0.z, h0.z) BNAPP(3, c0.w, h0.w)
      BNAPP(4, c1.x, h1.x) BNAPP(5, c1.y, h1.y) BNAPP(6, c1.z, h1.z) BNAPP(7, c1.w, h1.w)
#undef BNAPP
    }
#pragma unroll
    for (int t = 0; t < 8; ++t) {
      bf16x8 bfr = *(const bf16x8*)&sWt[(t * 16 + lr) * SAB_LD + kk + lk];
      acc[t] = __builtin_amdgcn_mfma_f32_16x16x32_bf16(af, bfr, acc[t], 0, 0, 0);
    }
  }
  // epilogue: scale by dinv, store ushort per lane (D row = 4*(l>>4)+j, col = t*16+lr)
  const int rbase = row0 + w * 16 + (l >> 4) * 4;
#pragma unroll
  for (int j = 0; j < 4; ++j) {
    int r = rbase + j;
    if (r >= N) continue;
    float d = dinv[r];
#pragma unroll
    for (int t = 0; t < 8; ++t) {
      Yp[(size_t)r * HD + t * 16 + lr] = (unsigned short)bf_round(acc[t][j] * d);
    }
  }
}

// ---------------- aggregate: Out[n] = bf16( dinv[n]*(Yp[n] + sum_{s in N(n)} Yp[s]) ) ----------------
// One wave per node; uint2 (8B) per lane so each wave-instruction fetches TWO neighbor
// rows (half 0 -> row j, half 1 -> row j+1). 8 loads in flight cover 16 rows.
__global__ __launch_bounds__(256) void k_aggregate(const unsigned* __restrict__ Yp,
                                                   const unsigned* __restrict__ nodeinfo,
                                                   const unsigned short* __restrict__ colidx,
                                                   const float* __restrict__ dinv,
                                                   unsigned* __restrict__ Out, int N) {
  int n = (blockIdx.x * blockDim.x + threadIdx.x) >> 6;  // one wave per node
  int lane = threadIdx.x & 63;
  if (n >= N) return;
  const int sl = lane & 31;
  const int hid = lane >> 5;   // half id: reads rows j+hid
  const unsigned info = nodeinfo[n];
  const int beg = (int)(info >> 8);
  const int deg = (int)(info & 255);
  float a0 = 0.f, a1 = 0.f, a2 = 0.f, a3 = 0.f;  // cols 4sl..4sl+3
  if (hid == 0) {  // self row once
    uint2 u = *(const uint2*)&Yp[(size_t)n * 64 + sl * 2];
    float2 p0 = bf_unpack2(u.x), p1 = bf_unpack2(u.y);
    a0 = p0.x; a1 = p0.y; a2 = p1.x; a3 = p1.y;
  }
  for (int base = 0; base < deg; base += 64) {
    int cnt = deg - base; if (cnt > 64) cnt = 64;
    int nbr = (lane < cnt) ? (int)colidx[beg + base + lane] : 0;
    int j = 0;
    for (; j + 16 <= cnt; j += 16) {  // 8 uint2 loads in flight = 16 rows
      int s0 = __shfl(nbr, j + 0 + hid, 64);
      int s1 = __shfl(nbr, j + 2 + hid, 64);
      int s2 = __shfl(nbr, j + 4 + hid, 64);
      int s3 = __shfl(nbr, j + 6 + hid, 64);
      int s4 = __shfl(nbr, j + 8 + hid, 64);
      int s5 = __shfl(nbr, j + 10 + hid, 64);
      int s6 = __shfl(nbr, j + 12 + hid, 64);
      int s7 = __shfl(nbr, j + 14 + hid, 64);
      uint2 q0 = *(const uint2*)&Yp[(size_t)s0 * 64 + sl * 2];
      uint2 q1 = *(const uint2*)&Yp[(size_t)s1 * 64 + sl * 2];
      uint2 q2 = *(const uint2*)&Yp[(size_t)s2 * 64 + sl * 2];
      uint2 q3 = *(const uint2*)&Yp[(size_t)s3 * 64 + sl * 2];
      uint2 q4 = *(const uint2*)&Yp[(size_t)s4 * 64 + sl * 2];
      uint2 q5 = *(const uint2*)&Yp[(size_t)s5 * 64 + sl * 2];
      uint2 q6 = *(const uint2*)&Yp[(size_t)s6 * 64 + sl * 2];
      uint2 q7 = *(const uint2*)&Yp[(size_t)s7 * 64 + sl * 2];
      float2 x0 = bf_unpack2(q0.x), y0 = bf_unpack2(q0.y);
      float2 x1 = bf_unpack2(q1.x), y1 = bf_unpack2(q1.y);
      float2 x2 = bf_unpack2(q2.x), y2 = bf_unpack2(q2.y);
      float2 x3 = bf_unpack2(q3.x), y3 = bf_unpack2(q3.y);
      float2 x4 = bf_unpack2(q4.x), y4 = bf_unpack2(q4.y);
      float2 x5 = bf_unpack2(q5.x), y5 = bf_unpack2(q5.y);
      float2 x6 = bf_unpack2(q6.x), y6 = bf_unpack2(q6.y);
      float2 x7 = bf_unpack2(q7.x), y7 = bf_unpack2(q7.y);
      a0 += ((x0.x + x1.x) + (x2.x + x3.x)) + ((x4.x + x5.x) + (x6.x + x7.x));
      a1 += ((x0.y + x1.y) + (x2.y + x3.y)) + ((x4.y + x5.y) + (x6.y + x7.y));
      a2 += ((y0.x + y1.x) + (y2.x + y3.x)) + ((y4.x + y5.x) + (y6.x + y7.x));
      a3 += ((y0.y + y1.y) + (y2.y + y3.y)) + ((y4.y + y5.y) + (y6.y + y7.y));
    }
    for (; j + 2 <= cnt; j += 2) {  // pair tail
      int s = __shfl(nbr, j + hid, 64);
      uint2 q = *(const uint2*)&Yp[(size_t)s * 64 + sl * 2];
      float2 x = bf_unpack2(q.x), y = bf_unpack2(q.y);
      a0 += x.x; a1 += x.y; a2 += y.x; a3 += y.y;
    }
    if (j < cnt) {  // odd last row: half 0 only
      int s = __shfl(nbr, j, 64);
      if (hid == 0) {
        uint2 q = *(const uint2*)&Yp[(size_t)s * 64 + sl * 2];
        float2 x = bf_unpack2(q.x), y = bf_unpack2(q.y);
        a0 += x.x; a1 += x.y; a2 += y.x; a3 += y.y;
      }
    }
  }
  // combine halves (cols identical across halves)
  a0 += __shfl_xor(a0, 32, 64);
  a1 += __shfl_xor(a1, 32, 64);
  a2 += __shfl_xor(a2, 32, 64);
  a3 += __shfl_xor(a3, 32, 64);
  if (hid == 0) {
    float dd = dinv[n];
    unsigned lo = bf_pack2(a0 * dd, a1 * dd);
    unsigned hi = bf_pack2(a2 * dd, a3 * dd);
    *(uint2*)&Out[(size_t)n * 64 + sl * 2] = make_uint2(lo, hi);
  }
}

// ---------------- per-column sum / sumsq over bf16-packed X ----------------
__global__ __launch_bounds__(256) void k_colstats(const unsigned* __restrict__ X, int N,
                                                  float* __restrict__ sums) {
  const int c2 = threadIdx.x & 63;   // packed col pair
  const int half = threadIdx.x >> 6; // 4-way row split
  float sx = 0.f, sy = 0.f, qx = 0.f, qy = 0.f;
  for (int r = blockIdx.x * 4 + half; r < N; r += gridDim.x * 4) {
    float2 v = bf_unpack2(X[(size_t)r * 64 + c2]);
    sx += v.x; sy += v.y; qx += v.x * v.x; qy += v.y * v.y;
  }
  __shared__ float l0[256], l1[256], l2[256], l3[256];
  l0[threadIdx.x] = sx; l1[threadIdx.x] = sy; l2[threadIdx.x] = qx; l3[threadIdx.x] = qy;
  __syncthreads();
  if (threadIdx.x < 64) {
    int t = threadIdx.x;
    sx = l0[t] + l0[t + 64] + l0[t + 128] + l0[t + 192];
    sy = l1[t] + l1[t + 64] + l1[t + 128] + l1[t + 192];
    qx = l2[t] + l2[t + 64] + l2[t + 128] + l2[t + 192];
    qy = l3[t] + l3[t + 64] + l3[t + 128] + l3[t + 192];
    int c = t * 2;
    atomicAdd(&sums[c], sx);
    atomicAdd(&sums[c + 1], sy);
    atomicAdd(&sums[128 + c], qx);
    atomicAdd(&sums[129 + c], qy);
  }
}

// ---------------- fused BN2+ReLU+dot(Wout) per node (atomic-free, BN params in-thread) ----------------
__global__ __launch_bounds__(256) void k_finalnode(const unsigned* __restrict__ Agg,
                                                   const float* __restrict__ sums,
                                                   const float* __restrict__ gamma,
                                                   const float* __restrict__ beta,
                                                   const float* __restrict__ wout,
                                                   float* __restrict__ nodescalar,
                                                   int N, float invN) {
  int n = (blockIdx.x * blockDim.x + threadIdx.x) >> 6;
  int lane = threadIdx.x & 63;
  if (n >= N) return;
  int c = lane * 2;
  float mean0 = sums[c] * invN;
  float var0 = sums[128 + c] * invN - mean0 * mean0;
  float sc0 = gamma[c] * rsqrtf(var0 + EPS);
  float sh0 = beta[c] - mean0 * sc0;
  float mean1 = sums[c + 1] * invN;
  float var1 = sums[129 + c] * invN - mean1 * mean1;
  float sc1 = gamma[c + 1] * rsqrtf(var1 + EPS);
  float sh1 = beta[c + 1] - mean1 * sc1;
  float2 v = bf_unpack2(Agg[(size_t)n * 64 + lane]);
  float h0 = fmaxf(0.f, v.x * sc0 + sh0);
  float h1 = fmaxf(0.f, v.y * sc1 + sh1);
  float p = h0 * wout[c] + h1 * wout[c + 1];
  for (int off = 32; off > 0; off >>= 1) p += __shfl_down(p, off);
  if (lane == 0) nodescalar[n] = p;
}

// mean over each graph's contiguous node range (batch sorted) via binary search
__global__ void k_finalout(const float* __restrict__ nodescalar, const int* __restrict__ batch,
                           const float* __restrict__ bout, float* __restrict__ out,
                           int G, int N) {
  int g = blockIdx.x * blockDim.x + threadIdx.x;
  if (g >= G) return;
  int lo = 0, hi = N;
  while (lo < hi) { int mid = (lo + hi) >> 1; if (batch[mid] < g) lo = mid + 1; else hi = mid; }
  int lb = lo;
  hi = N;
  while (lo < hi) { int mid = (lo + hi) >> 1; if (batch[mid] <= g) lo = mid + 1; else hi = mid; }
  float s = 0.f;
  for (int i = lb; i < lo; ++i) s += nodescalar[i];
  float cnt = (float)(lo - lb);
  out[g] = s / fmaxf(cnt, 1.0f) + bout[0];
}

extern "C" void kernel_launch(void* const* d_in, const int* in_sizes, int n_in,
                              void* d_out, int out_size, void* d_ws, size_t ws_size,
                              hipStream_t stream) {
  (void)n_in; (void)ws_size;
  const float* x      = (const float*)d_in[0];
  const int*   ei     = (const int*)d_in[1];
  const int*   batch  = (const int*)d_in[2];
  const float* W1     = (const float*)d_in[3];
  const float* gamma1 = (const float*)d_in[5];
  const float* beta1  = (const float*)d_in[6];
  const float* W2     = (const float*)d_in[7];
  const float* gamma2 = (const float*)d_in[9];
  const float* beta2  = (const float*)d_in[10];
  const float* wout   = (const float*)d_in[11];
  const float* bout   = (const float*)d_in[12];
  float* out = (float*)d_out;

  const int N = in_sizes[0] / HD;
  const int E = in_sizes[1] / 2;
  const int G = out_size;
  const int* src = ei;
  const int* dst = ei + E;
  const int NBKT = (N + NPB - 1) / NPB;
  const int NWGA = 256;
  const int chunk = (E + NWGA - 1) / NWGA;
  const int capLines = E / (NBKT * 16) + NWGA + 64;  // worst case: 1 partial line per wg per bucket
  const int capSlots = capLines * 16;
  const float invN = 1.0f / (float)N;

  char* p = (char*)d_ws;
  auto carve = [&](size_t bytes) { char* r = p; p += (bytes + 255) & ~(size_t)255; return r; };
  unsigned* bufY = (unsigned*)carve((size_t)N * 64 * 4);     // bf16 Y' [N,128] (ushort rows)
  unsigned* bufAgg = (unsigned*)carve((size_t)N * 64 * 4);   // bf16 Agg [N,128]
  unsigned* arena = (unsigned*)carve((size_t)NBKT * capSlots * 4);
  unsigned short* colidx = (unsigned short*)carve((size_t)NBKT * capSlots * 2);
  unsigned short* Wt1 = (unsigned short*)carve(128 * 128 * 2);
  unsigned short* Wt2 = (unsigned short*)carve(128 * 128 * 2);
  unsigned* nodeinfo = (unsigned*)carve((size_t)N * 4);
  float* dinv    = (float*)carve((size_t)N * 4);
  float* nodescalar = (float*)carve((size_t)N * 4);
  int*   bline = (int*)carve((size_t)NBKT * 16 * 4);
  float* sums1 = (float*)carve(256 * 4);
  float* sums2 = (float*)carve(256 * 4);

  const int nbline = NBKT * 16;
  const int pblocks = 128 + (nbline + 255) / 256;
  k_prep<<<pblocks, 256, 0, stream>>>(W1, W2, Wt1, Wt2, bline, sums1, sums2, nbline);

  // CSR build (2 kernels)
  k_phaseA<<<NWGA, 256, 0, stream>>>(src, dst, bline, arena, E, NBKT, capLines, chunk);
  k_phaseB<<<NBKT, 256, 0, stream>>>(arena, bline, colidx, nodeinfo, dinv, N, capLines);

  const int gblocks = (N + 63) / 64;
  const int ablocks = (N + 3) / 4;
  // layer 1 (A direct from f32 x)
  k_gemm<<<gblocks, 256, 0, stream>>>(x, nullptr, Wt1, (unsigned short*)bufY, N, dinv,
                                      nullptr, nullptr, nullptr, invN);
  k_aggregate<<<ablocks, 256, 0, stream>>>(bufY, nodeinfo, colidx, dinv, bufAgg, N);
  k_colstats<<<512, 256, 0, stream>>>(bufAgg, N, sums1);
  // layer 2 (A direct from bf16 bufAgg; BN1+ReLU fused in-register)
  k_gemm<<<gblocks, 256, 0, stream>>>(nullptr, (const unsigned short*)bufAgg, Wt2,
                                      (unsigned short*)bufY, N, dinv, sums1, gamma1, beta1, invN);
  k_aggregate<<<ablocks, 256, 0, stream>>>(bufY, nodeinfo, colidx, dinv, bufAgg, N);
  k_colstats<<<512, 256, 0, stream>>>(bufAgg, N, sums2);
  // pooling + output head (atomic-free; BN2 params in-thread)
  k_finalnode<<<ablocks, 256, 0, stream>>>(bufAgg, sums2, gamma2, beta2, wout, nodescalar, N, invN);
  k_finalout<<<(G + 255) / 256, 256, 0, stream>>>(nodescalar, batch, bout, out, G, N);
}